// Round 3
// baseline (1112.987 us; speedup 1.0000x reference)
//
#include <hip/hip_runtime.h>

typedef _Float16 half_t;
typedef _Float16 half8 __attribute__((ext_vector_type(8)));
typedef float floatx4 __attribute__((ext_vector_type(4)));

#define NSEQ   256      // B*S
#define TLEN   128
#define EMBD   512
#define UNITSZ 512
#define GC     2048     // 4*UNITS
#define NTOK   32768    // NSEQ*TLEN
#define NCOL   4096     // 2 dirs * GC
#define KDIM   512

// workspace layout (bytes)
constexpr size_t OFF_EMB = 0;                    // emb_f16: NTOK*512*2 = 33,554,432
constexpr size_t OFF_WT  = 33554432;             // WcatT fp16 [4096][512] = 4,194,304
constexpr size_t OFF_UT  = OFF_WT + 4194304;     // UcatT fp16 [4096][512] = 4,194,304
constexpr size_t OFF_HB  = OFF_UT + 4194304;     // hbuf fp16 [2dir][2par][256][512] = 1,048,576
constexpr size_t OFF_CNT = OFF_HB + 1048576;     // counters: 32 groups x 128B = 4096 B
constexpr size_t OFF_MSK = OFF_CNT + 4096;       // mask bits: 256 * 2 u64 = 4096 B
constexpr size_t OFF_XW  = OFF_MSK + 4096;       // xW fp16 [32768][4096] = 268,435,456

__device__ inline float sigm(float x)  { return 1.0f / (1.0f + __expf(-x)); }
__device__ inline float tanhx(float x) { return 2.0f / (1.0f + __expf(-2.0f * x)) - 1.0f; }

// ---------------------------------------------------------------------------
// Cross-block exchange primitives — PROVEN agent-scope semantics only
// (sc0 sc1 = bypass CU-L1 and XCD-L2; IF$/memory is the coherence point).
// R2's same-XCD L2-scope experiment produced stale reads (absmax 1.7e-2) —
// CDNA4 cache-policy bits do not behave as assumed; do not retry without a
// dedicated on-device probe.
// ---------------------------------------------------------------------------
__device__ inline unsigned ld_cnt(const unsigned* p) {
    unsigned v;
    asm volatile("global_load_dword %0, %1, off sc0 sc1\n\t"
                 "s_waitcnt vmcnt(0)" : "=v"(v) : "v"(p) : "memory");
    return v;
}

__device__ inline void st_h(unsigned short* p, unsigned v) {
    asm volatile("global_store_short %0, %1, off sc0 sc1" :: "v"(p), "v"(v) : "memory");
}

// issue 16x16B A-fragment loads (one K-step each), NO wait — caller fences
// with a counted s_waitcnt vmcnt(16) after issuing its own xW prefetch.
__device__ inline void af_issue(const half_t* ap, half8* af) {
    asm volatile(
        "global_load_dwordx4 %0, %16, off sc0 sc1\n\t"
        "global_load_dwordx4 %1, %16, off offset:64 sc0 sc1\n\t"
        "global_load_dwordx4 %2, %16, off offset:128 sc0 sc1\n\t"
        "global_load_dwordx4 %3, %16, off offset:192 sc0 sc1\n\t"
        "global_load_dwordx4 %4, %16, off offset:256 sc0 sc1\n\t"
        "global_load_dwordx4 %5, %16, off offset:320 sc0 sc1\n\t"
        "global_load_dwordx4 %6, %16, off offset:384 sc0 sc1\n\t"
        "global_load_dwordx4 %7, %16, off offset:448 sc0 sc1\n\t"
        "global_load_dwordx4 %8, %16, off offset:512 sc0 sc1\n\t"
        "global_load_dwordx4 %9, %16, off offset:576 sc0 sc1\n\t"
        "global_load_dwordx4 %10, %16, off offset:640 sc0 sc1\n\t"
        "global_load_dwordx4 %11, %16, off offset:704 sc0 sc1\n\t"
        "global_load_dwordx4 %12, %16, off offset:768 sc0 sc1\n\t"
        "global_load_dwordx4 %13, %16, off offset:832 sc0 sc1\n\t"
        "global_load_dwordx4 %14, %16, off offset:896 sc0 sc1\n\t"
        "global_load_dwordx4 %15, %16, off offset:960 sc0 sc1"
        : "=&v"(af[0]), "=&v"(af[1]), "=&v"(af[2]), "=&v"(af[3]),
          "=&v"(af[4]), "=&v"(af[5]), "=&v"(af[6]), "=&v"(af[7]),
          "=&v"(af[8]), "=&v"(af[9]), "=&v"(af[10]), "=&v"(af[11]),
          "=&v"(af[12]), "=&v"(af[13]), "=&v"(af[14]), "=&v"(af[15])
        : "v"(ap) : "memory");
}

// issue next-step xW prefetch (16 x 2B, immutable data, plain cached loads),
// NO wait — consumed next iteration, after the end-of-step vmcnt(0) drain.
__device__ inline void xv_issue(const half_t* p0, const half_t* p1,
                                const half_t* p2, const half_t* p3,
                                unsigned* xvr) {
    asm volatile(
        "global_load_ushort %0, %16, off\n\t"
        "global_load_ushort %1, %16, off offset:1024\n\t"
        "global_load_ushort %2, %16, off offset:2048\n\t"
        "global_load_ushort %3, %16, off offset:3072\n\t"
        "global_load_ushort %4, %17, off\n\t"
        "global_load_ushort %5, %17, off offset:1024\n\t"
        "global_load_ushort %6, %17, off offset:2048\n\t"
        "global_load_ushort %7, %17, off offset:3072\n\t"
        "global_load_ushort %8, %18, off\n\t"
        "global_load_ushort %9, %18, off offset:1024\n\t"
        "global_load_ushort %10, %18, off offset:2048\n\t"
        "global_load_ushort %11, %18, off offset:3072\n\t"
        "global_load_ushort %12, %19, off\n\t"
        "global_load_ushort %13, %19, off offset:1024\n\t"
        "global_load_ushort %14, %19, off offset:2048\n\t"
        "global_load_ushort %15, %19, off offset:3072"
        : "=&v"(xvr[0]), "=&v"(xvr[1]), "=&v"(xvr[2]), "=&v"(xvr[3]),
          "=&v"(xvr[4]), "=&v"(xvr[5]), "=&v"(xvr[6]), "=&v"(xvr[7]),
          "=&v"(xvr[8]), "=&v"(xvr[9]), "=&v"(xvr[10]), "=&v"(xvr[11]),
          "=&v"(xvr[12]), "=&v"(xvr[13]), "=&v"(xvr[14]), "=&v"(xvr[15])
        : "v"(p0), "v"(p1), "v"(p2), "v"(p3) : "memory");
}

// ---------------- pack W/U (fp32 [512][2048] per dir) -> transposed fp16 [dir*2048+gcol][512]
__global__ void pack_kernel(const float* __restrict__ Wf, const float* __restrict__ Uf,
                            const float* __restrict__ Wb, const float* __restrict__ Ub,
                            half_t* __restrict__ WT, half_t* __restrict__ UT) {
    int c = blockIdx.x * 256 + threadIdx.x;          // 524288 chunks total
    int arr = c >> 18;                               // 0 = W, 1 = U
    int r = c & 262143;                              // 262144 = 4096*64
    int kc = r >> 12;                                // 64 chunks of 8 k
    int gc = r & 4095;                               // lanes vary gc -> coalesced reads
    int dir = gc >> 11;
    int g = gc & 2047;
    const float* src = (arr == 0) ? (dir ? Wb : Wf) : (dir ? Ub : Uf);
    half_t* dst = (arr == 0) ? WT : UT;
    half8 v;
#pragma unroll
    for (int j = 0; j < 8; ++j)
        v[j] = (half_t)src[(size_t)(kc * 8 + j) * GC + g];
    *(half8*)(dst + (size_t)gc * KDIM + kc * 8) = v;
}

// ---------------- zero hbuf + counters
__global__ void zero_kernel(unsigned* __restrict__ hb_and_cnt) {
    int i = blockIdx.x * 256 + threadIdx.x;          // 263168 dwords
    if (i < 263168) hb_and_cnt[i] = 0u;
}

// ---------------- pack per-row validity masks: mk[n] = 128 bits of (x!=0)
__global__ void mask_kernel(const int* __restrict__ x, unsigned long long* __restrict__ mk) {
    int n = blockIdx.x;       // 256 blocks x 64 threads
    int l = threadIdx.x;
    unsigned long long b0 = __ballot(x[n * TLEN + l] != 0);
    unsigned long long b1 = __ballot(x[n * TLEN + 64 + l] != 0);
    if (l == 0) { mk[n * 2] = b0; mk[n * 2 + 1] = b1; }
}

// ---------------- gather: emb_f16[token][512] = fp16(emb_table[x[token]][:])
__global__ void gather_kernel(const int* __restrict__ x, const float* __restrict__ tab,
                              half_t* __restrict__ embf) {
    int g = blockIdx.x * 256 + threadIdx.x;          // 2,097,152 chunks of 8
    int token = g >> 6;
    int k = (g & 63) * 8;
    int id = x[token];
    const float* s = tab + (size_t)id * EMBD + k;
    float4 a = *(const float4*)(s);
    float4 b = *(const float4*)(s + 4);
    half8 v;
    v[0] = (half_t)a.x; v[1] = (half_t)a.y; v[2] = (half_t)a.z; v[3] = (half_t)a.w;
    v[4] = (half_t)b.x; v[5] = (half_t)b.y; v[6] = (half_t)b.z; v[7] = (half_t)b.w;
    *(half8*)(embf + (size_t)token * EMBD + k) = v;
}

// ---------------- GEMM: xW[32768][4096] = emb_f16 @ WcatT^T + bias, fp16 out
__global__ __launch_bounds__(256, 2) void gemm_kernel(const half_t* __restrict__ embf,
                                                      const half_t* __restrict__ WT,
                                                      const float* __restrict__ bf,
                                                      const float* __restrict__ bb,
                                                      half_t* __restrict__ xw) {
    __shared__ half_t As[128 * 40];   // [row][32+8pad]
    __shared__ half_t Bs[128 * 40];   // B^T tile: [col][32+8pad]
    int bx = blockIdx.x;
    int bm = bx & 255, bn = bx >> 8;
    int r0 = bm * 128, c0 = bn * 128;
    int tid = threadIdx.x;
    int w = tid >> 6, l = tid & 63;
    int q = l >> 4, cl = l & 15;
    int mq = (w >> 1) * 64, nq = (w & 1) * 64;

    floatx4 acc[4][4];
#pragma unroll
    for (int a = 0; a < 4; ++a)
#pragma unroll
        for (int b = 0; b < 4; ++b) acc[a][b] = (floatx4){0.f, 0.f, 0.f, 0.f};

    for (int kb = 0; kb < 16; ++kb) {
#pragma unroll
        for (int cc = 0; cc < 2; ++cc) {
            int c = tid + cc * 256;
            int row = c >> 2, qt = c & 3;
            half8 va = *(const half8*)(embf + (size_t)(r0 + row) * KDIM + kb * 32 + qt * 8);
            *(half8*)(As + row * 40 + qt * 8) = va;
            half8 vb = *(const half8*)(WT + (size_t)(c0 + row) * KDIM + kb * 32 + qt * 8);
            *(half8*)(Bs + row * 40 + qt * 8) = vb;
        }
        __syncthreads();
        half8 af[4], bfr[4];
#pragma unroll
        for (int mb = 0; mb < 4; ++mb)
            af[mb] = *(const half8*)(As + (mq + mb * 16 + cl) * 40 + q * 8);
#pragma unroll
        for (int nb = 0; nb < 4; ++nb)
            bfr[nb] = *(const half8*)(Bs + (nq + nb * 16 + cl) * 40 + q * 8);
#pragma unroll
        for (int mb = 0; mb < 4; ++mb)
#pragma unroll
            for (int nb = 0; nb < 4; ++nb)
                acc[mb][nb] = __builtin_amdgcn_mfma_f32_16x16x32_f16(af[mb], bfr[nb], acc[mb][nb], 0, 0, 0);
        __syncthreads();
    }
    // epilogue: + bias, store fp16
#pragma unroll
    for (int nb = 0; nb < 4; ++nb) {
        int col = c0 + nq + nb * 16 + cl;
        int dir = col >> 11, gcol = col & 2047;
        float bias = dir ? bb[gcol] : bf[gcol];
#pragma unroll
        for (int mb = 0; mb < 4; ++mb) {
#pragma unroll
            for (int r = 0; r < 4; ++r) {
                int row = r0 + mq + mb * 16 + q * 4 + r;
                xw[(size_t)row * NCOL + col] = (half_t)(acc[mb][nb][r] + bias);
            }
        }
    }
}

// ---------------------------------------------------------------------------
// Persistent bidirectional LSTM, 256 blocks x 256 threads, agent-scope
// exchange (proven protocol), structurally de-hopped vs the 1100us baseline:
//  - no LDS, no __syncthreads in the step loop: each lane loads its MFMA
//    A-frag straight from hbuf (16B contiguous per lane, same lane mapping as
//    the old LDS-staged path), every thread polls the group counter itself,
//    h written back per-thread (no Pk repack + barrier).
//  - xW prefetch issued right after the poll; fenced by counted vmcnt(16) so
//    the A-frags are waited on but the HBM prefetch keeps flying under the
//    MFMA+gates phase. End-of-step vmcnt(0) drains stores+prefetch before the
//    signal. sched_barrier(0) after every asm waitcnt (compiler hoist hazard).
//  - per-wave signal (l==0): each wave signals only after its own vmcnt(0)
//    drain, so cnt >= 32*t implies all 8 blocks x 4 waves drained h stores.
//  - all spins capped: a protocol bug terminates (wrong, measurable) instead
//    of hanging the harness.
// ---------------------------------------------------------------------------
__global__ __launch_bounds__(256, 1) void lstm_kernel(const half_t* __restrict__ xw,
                                                      const half_t* __restrict__ UT,
                                                      half_t* __restrict__ hbuf,
                                                      const unsigned long long* __restrict__ mk,
                                                      float* __restrict__ out,
                                                      unsigned* __restrict__ cnt) {
    int bx = blockIdx.x;
    int grp = bx & 31;              // group id (dir*16+rowg); members: bx = grp + 32*j
    int wgc = bx >> 5;              // member 0..7 = unit-column group
    int dir = grp >> 4;
    int rowg = grp & 15;
    int tid = threadIdx.x;
    int w = tid >> 6, l = tid & 63;
    int q = l >> 4, cl = l & 15;
    int cg = wgc * 4 + w;           // col-group 0..31
    int ub = cg * 16;               // unit base (per wave)
    int r0 = rowg * 16;             // sequence-row base

    // preload U B-frags into registers: bfrag[kk*4+cf], cf = gate (immutable, cached)
    half8 bfrag[64];
#pragma unroll
    for (int kk = 0; kk < 16; ++kk)
#pragma unroll
        for (int cf = 0; cf < 4; ++cf)
            bfrag[kk * 4 + cf] = *(const half8*)(UT + (size_t)(dir * 2048 + cf * 512 + ub + cl) * KDIM + kk * 32 + q * 8);

    // preload this thread's 4 rows' validity masks (128 bits each)
    unsigned long long mlo[4], mhi[4];
#pragma unroll
    for (int r = 0; r < 4; ++r) {
        int n = r0 + q * 4 + r;
        mlo[r] = mk[n * 2];
        mhi[r] = mk[n * 2 + 1];
    }

    float cs[4] = {0.f, 0.f, 0.f, 0.f};
    float hs[4] = {0.f, 0.f, 0.f, 0.f};
    unsigned* cptr = cnt + grp * 32;     // 128B stride: no line sharing between groups
    int colb = dir * 2048 + ub + cl;

    // per-thread hbuf pointers (A-frag read is 16B contiguous per lane)
    const half_t* ap0 = hbuf + (size_t)(dir * 2 + 0) * NSEQ * UNITSZ + (size_t)(r0 + cl) * UNITSZ + q * 8;
    const half_t* ap1 = ap0 + (size_t)NSEQ * UNITSZ;
    half_t* hw0 = hbuf + (size_t)(dir * 2 + 0) * NSEQ * UNITSZ + (size_t)(r0 + q * 4) * UNITSZ + ub + cl;
    half_t* hw1 = hw0 + (size_t)NSEQ * UNITSZ;

    // xW row bases for prefetch
    const half_t* xb0 = xw + (size_t)(r0 + q * 4 + 0) * TLEN * NCOL + colb;
    const half_t* xb1 = xw + (size_t)(r0 + q * 4 + 1) * TLEN * NCOL + colb;
    const half_t* xb2 = xw + (size_t)(r0 + q * 4 + 2) * TLEN * NCOL + colb;
    const half_t* xb3 = xw + (size_t)(r0 + q * 4 + 3) * TLEN * NCOL + colb;

    // prefetch xW for t=0 (bias already baked in)
    unsigned xvr[16];
    {
        int tI = dir ? 127 : 0;
        xv_issue(xb0 + (size_t)tI * NCOL, xb1 + (size_t)tI * NCOL,
                 xb2 + (size_t)tI * NCOL, xb3 + (size_t)tI * NCOL, xvr);
    }
    // make the t=0 xW prefetch (asm loads, untracked by compiler) safe to read
    asm volatile("s_waitcnt vmcnt(0)" ::: "memory");
    __builtin_amdgcn_sched_barrier(0);

#pragma unroll 1
    for (int t = 0; t < TLEN; ++t) {
        int tIdx = dir ? (127 - t) : t;
        int rpar = t & 1;
        // acc init from prefetched xW (drained by last step's vmcnt(0))
        floatx4 a0, a1, a2, a3;
#pragma unroll
        for (int r = 0; r < 4; ++r) {
            a0[r] = (float)__builtin_bit_cast(half_t, (unsigned short)xvr[r * 4 + 0]);
            a1[r] = (float)__builtin_bit_cast(half_t, (unsigned short)xvr[r * 4 + 1]);
            a2[r] = (float)__builtin_bit_cast(half_t, (unsigned short)xvr[r * 4 + 2]);
            a3[r] = (float)__builtin_bit_cast(half_t, (unsigned short)xvr[r * 4 + 3]);
        }
        half8 af[16];
        if (t > 0) {
            unsigned tgt = 32u * (unsigned)t;
            for (unsigned sp = 0;; ++sp) {
                if (ld_cnt(cptr) >= tgt) break;
                if (sp >= (1u << 20)) break;            // hang-safety: fail measurably
                __builtin_amdgcn_s_sleep(1);
            }
            af_issue(rpar ? ap1 : ap0, af);             // 16 loads, no wait yet
        }
        {
            int tN = dir ? (t >= 126 ? 0 : 126 - t) : (t >= 127 ? 127 : t + 1);
            xv_issue(xb0 + (size_t)tN * NCOL, xb1 + (size_t)tN * NCOL,
                     xb2 + (size_t)tN * NCOL, xb3 + (size_t)tN * NCOL, xvr);
        }
        if (t > 0) {
            // wait for the 16 af loads; leave the 16 xW prefetches in flight
            asm volatile("s_waitcnt vmcnt(16)" ::: "memory");
            __builtin_amdgcn_sched_barrier(0);
#pragma unroll
            for (int kk = 0; kk < 16; ++kk) {
                a0 = __builtin_amdgcn_mfma_f32_16x16x32_f16(af[kk], bfrag[kk * 4 + 0], a0, 0, 0, 0);
                a1 = __builtin_amdgcn_mfma_f32_16x16x32_f16(af[kk], bfrag[kk * 4 + 1], a1, 0, 0, 0);
                a2 = __builtin_amdgcn_mfma_f32_16x16x32_f16(af[kk], bfrag[kk * 4 + 2], a2, 0, 0, 0);
                a3 = __builtin_amdgcn_mfma_f32_16x16x32_f16(af[kk], bfrag[kk * 4 + 3], a3, 0, 0, 0);
            }
        }
        // gates + masked state update (mask from registers), direct h store
        unsigned short* hdst = (unsigned short*)(rpar ? hw0 : hw1);
#pragma unroll
        for (int r = 0; r < 4; ++r) {
            unsigned long long mw = (tIdx & 64) ? mhi[r] : mlo[r];
            bool keep = (mw >> (tIdx & 63)) & 1ull;
            float iv = sigm(a0[r]);
            float fv = sigm(a1[r]);
            float gv = tanhx(a2[r]);
            float ov = sigm(a3[r]);
            float cn = fv * cs[r] + iv * gv;
            float hn = ov * tanhx(cn);
            if (keep) { cs[r] = cn; hs[r] = hn; }
            unsigned hv = (unsigned)__builtin_bit_cast(unsigned short, (half_t)hs[r]);
            st_h(hdst + r * 512, hv);
        }
        // drain h stores (and the xW prefetch) before signalling
        asm volatile("s_waitcnt vmcnt(0)" ::: "memory");
        __builtin_amdgcn_sched_barrier(0);
        if (l == 0)
            __hip_atomic_fetch_add(cptr, 1u, __ATOMIC_RELAXED, __HIP_MEMORY_SCOPE_AGENT);
    }
    // final output: out[n][dir*512 + unit]
#pragma unroll
    for (int r = 0; r < 4; ++r) {
        int n = r0 + q * 4 + r;
        out[(size_t)n * 1024 + dir * 512 + ub + cl] = hs[r];
    }
}

extern "C" void kernel_launch(void* const* d_in, const int* in_sizes, int n_in,
                              void* d_out, int out_size, void* d_ws, size_t ws_size,
                              hipStream_t stream) {
    const int*   x    = (const int*)d_in[0];
    const float* tab  = (const float*)d_in[1];
    const float* Wf   = (const float*)d_in[2];
    const float* Uf   = (const float*)d_in[3];
    const float* bf   = (const float*)d_in[4];
    const float* Wb   = (const float*)d_in[5];
    const float* Ub   = (const float*)d_in[6];
    const float* bb   = (const float*)d_in[7];
    float* out = (float*)d_out;

    char* ws = (char*)d_ws;
    half_t*   embf = (half_t*)(ws + OFF_EMB);
    half_t*   WT   = (half_t*)(ws + OFF_WT);
    half_t*   UT   = (half_t*)(ws + OFF_UT);
    half_t*   hbuf = (half_t*)(ws + OFF_HB);
    unsigned* cnt  = (unsigned*)(ws + OFF_CNT);
    unsigned long long* mkb = (unsigned long long*)(ws + OFF_MSK);
    half_t*   xw   = (half_t*)(ws + OFF_XW);
    unsigned* hbz  = (unsigned*)(ws + OFF_HB);   // zero range covers hbuf + cnt (contiguous)

    pack_kernel<<<2048, 256, 0, stream>>>(Wf, Uf, Wb, Ub, WT, UT);
    zero_kernel<<<1028, 256, 0, stream>>>(hbz);
    mask_kernel<<<256, 64, 0, stream>>>(x, mkb);
    gather_kernel<<<8192, 256, 0, stream>>>(x, tab, embf);
    gemm_kernel<<<8192, 256, 0, stream>>>(embf, WT, bf, bb, xw);
    lstm_kernel<<<256, 256, 0, stream>>>(xw, UT, hbuf, mkb, out, cnt);
}